// Round 3
// baseline (145.387 us; speedup 1.0000x reference)
//
#include <hip/hip_runtime.h>

// Problem constants (from reference): T=64, B=512, H=512, SEQ=384.
#define T_DIM 64
#define B_DIM 512
#define H_DIM 512
#define H4    (H_DIM / 4)   // 128 float4 per row

// Native clang vector type: __builtin_nontemporal_store rejects HIP's
// HIP_vector_type<float,4> struct but accepts ext_vector_type. Same 16B
// layout and dwordx4 codegen.
typedef float vfloat4 __attribute__((ext_vector_type(4)));

// R1-winner structure (118.3 us): grid 2048 = B * 4 quarters of T, block 256.
//
// *** DIAGNOSTIC ROUND: kernel_launch launches this kernel 3x back-to-back.
// The kernel is idempotent (reads in/init/ops, writes only out, no RAW), so
// output is bit-identical. Purpose: the harness top-5 is monopolized by
// ~42us poison fills, hiding our kernel's counters. With 3 dispatches the
// kernel enters top-5 and we read its dur_us / FETCH_SIZE / WRITE_SIZE /
// Occupancy directly instead of inferring them from dur_us arithmetic. ***
//
// Phase 1 (per wave, no barriers): lane t computes src[t] for this block's b:
//   pos_t  = inclusive prefix sum of ops[:,b]        (6 __shfl_up steps)
//   w_t    = pos_t - op_t + 1                        (slot written at step t)
//   src_t  = last t' <= t with w_{t'} == pos_t, else -1 (-1 => initial_hidden)
// via per-wave LDS table masks[65]: bit t' set in masks[w_{t'}], then
// src_t = MSB of (masks[pos_t] & bits[0..t]). Slot 0 never written (w >= 1)
// so pos_t == 0 naturally yields -1. pos_t <= t+1 <= 64, w <= 64.
//
// Phase 2: src broadcast via __shfl + readfirstlane (row base in SGPRs ->
// s[base]+v_off+imm addressing); all 8 loads issued before any store.
// Nontemporal stores (out never re-read) keep L2 for gather re-reads.
//
// XCD swizzle: 2048 = 8 XCDs * 256; remap so each XCD owns 64 consecutive
// b's INCLUDING all 4 t-quarters -> cross-quarter duplicate gathers hit the
// local 4 MiB L2 (per-XCD read set ~3 MiB) instead of L3/HBM.
__global__ __launch_bounds__(256) void state_stack_fused(
        const vfloat4* __restrict__ in,    // (T*B, H4)
        const vfloat4* __restrict__ init,  // (H4,)
        const int*     __restrict__ ops,   // (T, B)
        vfloat4*       __restrict__ out) { // (T*B, H4)
    const unsigned swz = ((blockIdx.x & 7u) << 8) | (blockIdx.x >> 3);  // bijective: 2048 = 8*256
    const int b    = swz >> 2;
    const int tq   = swz & 3;             // which 16-row quarter of T
    const int wave = threadIdx.x >> 6;
    const int lane = threadIdx.x & 63;

    // ---- Phase 1: wave-parallel src computation (lane == step t) ----
    const int op = ops[lane * B_DIM + b];
    int pos = op;
#pragma unroll
    for (int d = 1; d < 64; d <<= 1) {
        int n = __shfl_up(pos, d, 64);
        if (lane >= d) pos += n;
    }
    const int w = pos - op + 1;           // write slot at this step, in [1,64]

    __shared__ unsigned long long masks[4][65];
    masks[wave][lane] = 0ull;
    if (lane == 0) masks[wave][64] = 0ull;
    __builtin_amdgcn_wave_barrier();      // keep LDS ops in program order
    atomicOr(&masks[wave][w], 1ull << lane);
    __builtin_amdgcn_wave_barrier();
    unsigned long long m = masks[wave][pos];
    m &= (lane == 63) ? ~0ull : ((1ull << (lane + 1)) - 1ull);
    const int my_src = m ? (63 - __builtin_clzll(m)) : -1;

    // ---- Phase 2: gather 4 rows of 2 KiB each ----
    const int t0 = tq * 16 + wave * 4;

    // Row bases: src is wave-uniform (shfl broadcast) -> readfirstlane lets
    // the compiler keep the whole base address scalar (SALU + s-reg loads).
    const vfloat4* srow[4];
#pragma unroll
    for (int r = 0; r < 4; ++r) {
        const int s = __builtin_amdgcn_readfirstlane(__shfl(my_src, t0 + r, 64));
        srow[r] = (s < 0) ? init : in + ((size_t)(s * B_DIM + b)) * H4;
    }

    // All 8 loads in flight before any store (explicit MLP).
    vfloat4 v0[4], v1[4];
#pragma unroll
    for (int r = 0; r < 4; ++r) {
        v0[r] = srow[r][lane];
        v1[r] = srow[r][lane + 64];       // +1024 B folds into offset: imm
    }

#pragma unroll
    for (int r = 0; r < 4; ++r) {
        vfloat4* dst = out + ((size_t)((t0 + r) * B_DIM + b)) * H4;
        __builtin_nontemporal_store(v0[r], dst + lane);
        __builtin_nontemporal_store(v1[r], dst + lane + 64);
    }
}

extern "C" void kernel_launch(void* const* d_in, const int* in_sizes, int n_in,
                              void* d_out, int out_size, void* d_ws, size_t ws_size,
                              hipStream_t stream) {
    const float* inputs = (const float*)d_in[0];   // (T,B,H) fp32
    const float* init   = (const float*)d_in[1];   // (H,) fp32
    const int*   ops    = (const int*)d_in[2];     // (T,B) int32
    // d_in[3] = seq_len (only sizes the reference's stack; unused here)

    // DIAGNOSTIC: 3 idempotent launches so the kernel's own counters surface
    // in the top-5 dispatch table (normally monopolized by harness fills).
    // Launch 1 = representative (cold-ish); launches 2-3 = warm L2/L3.
    for (int rep = 0; rep < 3; ++rep) {
        state_stack_fused<<<B_DIM * 4, 256, 0, stream>>>(
            (const vfloat4*)inputs, (const vfloat4*)init, ops, (vfloat4*)d_out);
    }
}

// Round 4
// 117.343 us; speedup vs baseline: 1.2390x; 1.2390x over previous
//
#include <hip/hip_runtime.h>

// Problem constants (from reference): T=64, B=512, H=512, SEQ=384.
#define T_DIM 64
#define B_DIM 512
#define H_DIM 512
#define H4    (H_DIM / 4)   // 128 float4 per row

// Native clang vector type: __builtin_nontemporal_store rejects HIP's
// HIP_vector_type<float,4> struct but accepts ext_vector_type. Same 16B
// layout and dwordx4 codegen.
typedef float vfloat4 __attribute__((ext_vector_type(4)));

// FINAL: R1-winner structure. Grid 2048 = B * 4 quarters of T, block 256.
//
// Measured (R3 diagnostic, 3x idempotent launches): warm kernel = 13.6 us.
// Mandatory traffic = 64 MiB NT writes + ~22 MB deduplicated gather reads
// ~= 90 MB -> 13.8-14.3 us at the 6.3-6.5 TB/s achievable ceiling. The
// kernel is within ~2% of the memory roofline; the rest of dur_us is
// harness poison fills (2 x 42 us at ~80% peak write BW) + restores.
//
// Phase 1 (per wave, no barriers): lane t computes src[t] for this block's b:
//   pos_t  = inclusive prefix sum of ops[:,b]        (6 __shfl_up steps)
//   w_t    = pos_t - op_t + 1                        (slot written at step t)
//   src_t  = last t' <= t with w_{t'} == pos_t, else -1 (-1 => initial_hidden)
// via per-wave LDS table masks[65]: bit t' set in masks[w_{t'}], then
// src_t = MSB of (masks[pos_t] & bits[0..t]). Slot 0 never written (w >= 1)
// so pos_t == 0 naturally yields -1. pos_t <= t+1 <= 64, w <= 64.
//
// Phase 2: src broadcast via __shfl + readfirstlane (row base in SGPRs ->
// s[base]+v_off+imm addressing); all 8 loads issued before any store
// (explicit MLP). Nontemporal stores (out never re-read) keep L2 for the
// gather re-reads of input rows.
//
// XCD swizzle: 2048 = 8 XCDs * 256; dispatch j lands on XCD j%8 (round-robin
// heuristic, perf-only). Remap so each XCD owns 64 consecutive b's INCLUDING
// all 4 t-quarters -> cross-quarter duplicate gathers (op in {0,-1} re-reading
// rows an earlier quarter already fetched) hit the local 4 MiB L2 (per-XCD
// read set ~3 MiB) instead of going to L3/HBM. Measured A/B: -2.8 us total.
//
// Rejected variants (measured):
//   - 4096-block oversubscription (R2): +1.9 us — fills saturate HBM at 8.5%
//     occupancy, so backfill/MLP was never the limiter; doubled Phase-1
//     redundancy was pure cost.
__global__ __launch_bounds__(256) void state_stack_fused(
        const vfloat4* __restrict__ in,    // (T*B, H4)
        const vfloat4* __restrict__ init,  // (H4,)
        const int*     __restrict__ ops,   // (T, B)
        vfloat4*       __restrict__ out) { // (T*B, H4)
    const unsigned swz = ((blockIdx.x & 7u) << 8) | (blockIdx.x >> 3);  // bijective: 2048 = 8*256
    const int b    = swz >> 2;
    const int tq   = swz & 3;             // which 16-row quarter of T
    const int wave = threadIdx.x >> 6;
    const int lane = threadIdx.x & 63;

    // ---- Phase 1: wave-parallel src computation (lane == step t) ----
    const int op = ops[lane * B_DIM + b];
    int pos = op;
#pragma unroll
    for (int d = 1; d < 64; d <<= 1) {
        int n = __shfl_up(pos, d, 64);
        if (lane >= d) pos += n;
    }
    const int w = pos - op + 1;           // write slot at this step, in [1,64]

    __shared__ unsigned long long masks[4][65];
    masks[wave][lane] = 0ull;
    if (lane == 0) masks[wave][64] = 0ull;
    __builtin_amdgcn_wave_barrier();      // keep LDS ops in program order
    atomicOr(&masks[wave][w], 1ull << lane);
    __builtin_amdgcn_wave_barrier();
    unsigned long long m = masks[wave][pos];
    m &= (lane == 63) ? ~0ull : ((1ull << (lane + 1)) - 1ull);
    const int my_src = m ? (63 - __builtin_clzll(m)) : -1;

    // ---- Phase 2: gather 4 rows of 2 KiB each ----
    const int t0 = tq * 16 + wave * 4;

    // Row bases: src is wave-uniform (shfl broadcast) -> readfirstlane lets
    // the compiler keep the whole base address scalar (SALU + s-reg loads).
    const vfloat4* srow[4];
#pragma unroll
    for (int r = 0; r < 4; ++r) {
        const int s = __builtin_amdgcn_readfirstlane(__shfl(my_src, t0 + r, 64));
        srow[r] = (s < 0) ? init : in + ((size_t)(s * B_DIM + b)) * H4;
    }

    // All 8 loads in flight before any store (explicit MLP).
    vfloat4 v0[4], v1[4];
#pragma unroll
    for (int r = 0; r < 4; ++r) {
        v0[r] = srow[r][lane];
        v1[r] = srow[r][lane + 64];       // +1024 B folds into offset: imm
    }

#pragma unroll
    for (int r = 0; r < 4; ++r) {
        vfloat4* dst = out + ((size_t)((t0 + r) * B_DIM + b)) * H4;
        __builtin_nontemporal_store(v0[r], dst + lane);
        __builtin_nontemporal_store(v1[r], dst + lane + 64);
    }
}

extern "C" void kernel_launch(void* const* d_in, const int* in_sizes, int n_in,
                              void* d_out, int out_size, void* d_ws, size_t ws_size,
                              hipStream_t stream) {
    const float* inputs = (const float*)d_in[0];   // (T,B,H) fp32
    const float* init   = (const float*)d_in[1];   // (H,) fp32
    const int*   ops    = (const int*)d_in[2];     // (T,B) int32
    // d_in[3] = seq_len (only sizes the reference's stack; unused here)

    state_stack_fused<<<B_DIM * 4, 256, 0, stream>>>(
        (const vfloat4*)inputs, (const vfloat4*)init, ops, (vfloat4*)d_out);
}